// Round 8
// baseline (256.376 us; speedup 1.0000x reference)
//
#include <hip/hip_runtime.h>

typedef unsigned int u32;
typedef unsigned short u16;
typedef unsigned long long u64;

typedef __attribute__((ext_vector_type(8))) short s8v;   // 8 bf16 (4 VGPRs)
typedef __attribute__((ext_vector_type(4))) float f4v;   // 4 fp32 acc

#define B_SZ   8192
#define V_SZ   1000
#define KCH    5
#define MAXDEG 32

__device__ __forceinline__ u16 f2bf(float f) {
    u32 u = __float_as_uint(f);
    u32 r = (u + 0x7FFFu + ((u >> 16) & 1u)) >> 16;   // RNE
    return (u16)r;
}
__device__ __forceinline__ float bf2f(u16 h) { return __uint_as_float(((u32)h) << 16); }

// ---------------------------------------------------------------------------
// K0: fused prep = {sparse build of Lr} U {weight bf16 conversion + BN fold}.
// blocks 0..249: build (wave-per-row scan of dense L, transposed packed4 out)
// blocks 250..889: weight conversion work.
// packed4[q4*V + v] int4 = entries 4q4..4q4+3 of row v (coalesced in k_cheby);
// entry = (fp32 weight, low 10 mantissa bits cleared) | col(10b); tail = 0.
// ---------------------------------------------------------------------------
__global__ __launch_bounds__(256) void k_prep(const float* __restrict__ L,
                                              const float* __restrict__ lmax,
                                              u32* __restrict__ packed,
                                              int* __restrict__ cnts,
                                              float* __restrict__ diagw,
                                              const float* __restrict__ fc1W,
                                              const float* __restrict__ lin1W,
                                              const float* __restrict__ gam,
                                              const float* __restrict__ bet,
                                              const float* __restrict__ mea,
                                              const float* __restrict__ var,
                                              u16* __restrict__ fc1w_b,
                                              u16* __restrict__ lin1w_b,
                                              float* __restrict__ bn_a,
                                              float* __restrict__ bn_c) {
    if (blockIdx.x < 250) {
        int wid  = threadIdx.x >> 6;
        int lane = threadIdx.x & 63;
        int row  = blockIdx.x * 4 + wid;
        if (row >= V_SZ) return;
        float s = 2.0f / lmax[0];
        const float* Lrow = L + (u64)row * V_SZ;
        int cnt = 0;
        for (int c0 = 0; c0 < V_SZ; c0 += 64) {
            int c = c0 + lane;
            float val = 0.0f;
            if (c < V_SZ && c != row) val = Lrow[c];
            bool nz = (val != 0.0f);
            u64 m = __ballot(nz);
            int pos = cnt + __popcll(m & ((1ull << lane) - 1ull));
            if (nz && pos < MAXDEG) {
                u32 w = __float_as_uint(val * s);
                packed[((pos >> 2) * V_SZ + row) * 4 + (pos & 3)] = (w & 0xFFFFFC00u) | (u32)c;
            }
            cnt += __popcll(m);
        }
        int cc = cnt < MAXDEG ? cnt : MAXDEG;
        for (int e = cc + lane; e < MAXDEG; e += 64)
            packed[((e >> 2) * V_SZ + row) * 4 + (e & 3)] = 0;
        if (lane == 0) {
            cnts[row]  = cc;
            diagw[row] = s * Lrow[row] - 1.0f;
        }
    } else {
        int t = (blockIdx.x - 250) * 256 + threadIdx.x;
        if (t < 256 * 640) {
            int r = t / 640, c = t - r * 640;
            fc1w_b[t] = (c < 625) ? f2bf(fc1W[r * 625 + c]) : (u16)0;
        }
        if (t < 256 * 256) lin1w_b[t] = f2bf(lin1W[t]);
        if (t < 4 * 256) {
            float a = gam[t] * rsqrtf(var[t] + 1e-5f);
            bn_a[t] = a;
            bn_c[t] = bet[t] - mea[t] * a;
        }
    }
}

// ---------------------------------------------------------------------------
// K1: fused Chebyshev recursion + cl1 + ReLU + maxpool8 -> bf16.
// 1024 threads, 1 row/thread, 8 batch cols/block (1024 blocks):
// per-quad decode+address serves 8 columns (-28% VALU/col vs 4-col round 5).
// Ping-pong float8 stage buffers = 64 KB LDS. Per neighbor: one addr calc,
// 2x ds_read_b128 (second via +16B offset), 8 FMA. feat = 40 VGPR (1 row).
// 1024-thr block => hard 128-VGPR cap; spill tripwire = WRITE_SIZE >> 10.3MB.
// ---------------------------------------------------------------------------
__global__ __launch_bounds__(1024) void k_cheby(const float* __restrict__ x,
                                                const int4* __restrict__ packed4,
                                                const int* __restrict__ cnts,
                                                const float* __restrict__ diagw,
                                                const float* __restrict__ cl1W,
                                                const float* __restrict__ cl1b,
                                                u16* __restrict__ pooled) {
    __shared__ float buf[2][V_SZ * 8];   // [pingpong][v*8 + c] = 64 KB
    __shared__ float cws[25];
    __shared__ float cbs[5];
    int t  = threadIdx.x;
    int b0 = blockIdx.x * 8;

    if (t < 25) cws[t] = cl1W[t];
    if (t < 5)  cbs[t] = cl1b[t];

    const bool own = (t < V_SZ);

    float d0 = 0.0f;
    int   n0 = 0;
    if (own) { d0 = diagw[t]; n0 = (cnts[t] + 3) >> 2; }

    // stage-0 staging: buf[0][t*8 + b] = x[b0+b][t]; own values kept in regs
    float4 pm1l, pm1h, pm2l, pm2h;
    pm1l = make_float4(0.f, 0.f, 0.f, 0.f);
    pm1h = pm1l;
    if (own) {
        pm1l.x = x[(u64)(b0 + 0) * V_SZ + t];
        pm1l.y = x[(u64)(b0 + 1) * V_SZ + t];
        pm1l.z = x[(u64)(b0 + 2) * V_SZ + t];
        pm1l.w = x[(u64)(b0 + 3) * V_SZ + t];
        pm1h.x = x[(u64)(b0 + 4) * V_SZ + t];
        pm1h.y = x[(u64)(b0 + 5) * V_SZ + t];
        pm1h.z = x[(u64)(b0 + 6) * V_SZ + t];
        pm1h.w = x[(u64)(b0 + 7) * V_SZ + t];
        *(float4*)(&buf[0][t * 8])     = pm1l;
        *(float4*)(&buf[0][t * 8 + 4]) = pm1h;
    }
    pm2l = pm1l; pm2h = pm1h;
    __syncthreads();

    // feat init with k=0 term
    float4 fl[5], fh[5];
#pragma unroll
    for (int f = 0; f < 5; ++f) {
        float w = cws[f * 5];
        fl[f] = make_float4(w * pm1l.x, w * pm1l.y, w * pm1l.z, w * pm1l.w);
        fh[f] = make_float4(w * pm1h.x, w * pm1h.y, w * pm1h.z, w * pm1h.w);
    }

    // stages 1..4
#pragma unroll
    for (int k = 1; k < KCH; ++k) {
        const float* prevb = buf[(k - 1) & 1];
        float*       curb  = buf[k & 1];

        if (own) {
            float4 al = make_float4(d0 * pm1l.x, d0 * pm1l.y, d0 * pm1l.z, d0 * pm1l.w);
            float4 ah = make_float4(d0 * pm1h.x, d0 * pm1h.y, d0 * pm1h.z, d0 * pm1h.w);
            int4 pw = packed4[t];
            for (int q = 0; q < n0; ++q) {
                int4 pwn = pw;
                if (q + 1 < n0) pwn = packed4[(q + 1) * V_SZ + t];
#pragma unroll
                for (int e = 0; e < 4; ++e) {
                    u32 ent = (u32)((e == 0) ? pw.x : (e == 1) ? pw.y : (e == 2) ? pw.z : pw.w);
                    float w = __uint_as_float(ent & 0xFFFFFC00u);
                    const float4* p = (const float4*)(prevb + (ent & 1023u) * 8);
                    float4 gl = p[0];
                    float4 gh = p[1];
                    al.x = fmaf(w, gl.x, al.x); al.y = fmaf(w, gl.y, al.y);
                    al.z = fmaf(w, gl.z, al.z); al.w = fmaf(w, gl.w, al.w);
                    ah.x = fmaf(w, gh.x, ah.x); ah.y = fmaf(w, gh.y, ah.y);
                    ah.z = fmaf(w, gh.z, ah.z); ah.w = fmaf(w, gh.w, ah.w);
                }
                pw = pwn;
            }
            if (k >= 2) {
                al.x = fmaf(2.0f, al.x, -pm2l.x); al.y = fmaf(2.0f, al.y, -pm2l.y);
                al.z = fmaf(2.0f, al.z, -pm2l.z); al.w = fmaf(2.0f, al.w, -pm2l.w);
                ah.x = fmaf(2.0f, ah.x, -pm2h.x); ah.y = fmaf(2.0f, ah.y, -pm2h.y);
                ah.z = fmaf(2.0f, ah.z, -pm2h.z); ah.w = fmaf(2.0f, ah.w, -pm2h.w);
            }
            *(float4*)(&curb[t * 8])     = al;
            *(float4*)(&curb[t * 8 + 4]) = ah;
            pm2l = pm1l; pm2h = pm1h;
            pm1l = al;   pm1h = ah;
#pragma unroll
            for (int f = 0; f < 5; ++f) {
                float w = cws[f * 5 + k];
                fl[f].x = fmaf(w, al.x, fl[f].x); fl[f].y = fmaf(w, al.y, fl[f].y);
                fl[f].z = fmaf(w, al.z, fl[f].z); fl[f].w = fmaf(w, al.w, fl[f].w);
                fh[f].x = fmaf(w, ah.x, fh[f].x); fh[f].y = fmaf(w, ah.y, fh[f].y);
                fh[f].z = fmaf(w, ah.z, fh[f].z); fh[f].w = fmaf(w, ah.w, fh[f].w);
            }
        }
        __syncthreads();
    }

    // bias + ReLU + maxpool8 via 8-lane shuffle (8 consecutive t = 8 consecutive v)
#pragma unroll
    for (int f = 0; f < 5; ++f) {
#pragma unroll
        for (int b = 0; b < 8; ++b) {
            float c0 = (b == 0) ? fl[f].x : (b == 1) ? fl[f].y
                     : (b == 2) ? fl[f].z : (b == 3) ? fl[f].w
                     : (b == 4) ? fh[f].x : (b == 5) ? fh[f].y
                     : (b == 6) ? fh[f].z : fh[f].w;
            float s = own ? fmaxf(c0 + cbs[f], 0.0f) : 0.0f;
            s = fmaxf(s, __shfl_xor(s, 1));
            s = fmaxf(s, __shfl_xor(s, 2));
            s = fmaxf(s, __shfl_xor(s, 4));
            if ((t & 7) == 0 && own)
                pooled[(u64)(b0 + b) * 640 + (t >> 3) * 5 + f] = f2bf(s);
        }
    }
    // zero the K-padding columns 625..639 for the 8 batch rows
    if (t < 120) {
        int b = t / 15, c = 625 + (t % 15);
        pooled[(u64)(b0 + b) * 640 + c] = 0;
    }
}

// ---------------------------------------------------------------------------
// K2: fused tail. One block = 64 batch rows end-to-end:
//   z  = JKmax(BNx4(relu-chain)) of (pooled[64,640] @ fc1W^T + b)   -> LDS
//   z2 = relu(z @ lin1W^T + b1)                                    -> LDS
//   out= log_softmax(z2 @ l2W^T + b2)                              -> global
// 256 thr (4 waves); wave w owns rows w*16..+16 for ALL phases -> no
// cross-wave LDS hazards on zs. Weights streamed in 64-wide K-tiles via Bs.
// NOTE: Bs indices are TILE-RELATIVE, zs indices ABSOLUTE (round-6 NaN bug).
// ---------------------------------------------------------------------------
__global__ __launch_bounds__(256) void k_tail(const u16* __restrict__ A,      // pooled [B,640]
                                              const u16* __restrict__ W0,     // fc1w_b [256,640]
                                              const float* __restrict__ b0v,  // fc1b
                                              const float* __restrict__ bn_a,
                                              const float* __restrict__ bn_c,
                                              const u16* __restrict__ W1,     // lin1w_b [256,256]
                                              const float* __restrict__ b1v,  // lin1b
                                              const float* __restrict__ W2,   // l2W [10,256] f32
                                              const float* __restrict__ b2v,  // l2b
                                              float* __restrict__ out) {
    __shared__ u16   As[64][72];     // A-tile, +8 pad (stride 36 dw: 2-way free)
    __shared__ u16   Bs[256][72];    // weight K-tile
    __shared__ u16   zs[64][264];    // z / z2, stride 132 dw (=4 mod 32: 2-way)
    __shared__ float w2s[2560];
    __shared__ float b2s[10];
    int t    = threadIdx.x;
    int lane = t & 63;
    int wid  = t >> 6;
    int r0   = blockIdx.x * 64;

    for (int c = t; c < 2560; c += 256) w2s[c] = W2[c];
    if (t < 10) b2s[t] = b2v[t];

    f4v acc[16];
#pragma unroll
    for (int j = 0; j < 16; ++j) acc[j] = (f4v){0.f, 0.f, 0.f, 0.f};

    // ---------------- phase A: z = pooled @ W0^T (K=640) ----------------
    for (int k0 = 0; k0 < 640; k0 += 64) {
        int4 ra[2], rb[8];
#pragma unroll
        for (int i = 0; i < 2; ++i) {
            int c = t + i * 256, row = c >> 3, kc = c & 7;
            ra[i] = *(const int4*)(A + (u64)(r0 + row) * 640 + k0 + kc * 8);
        }
#pragma unroll
        for (int i = 0; i < 8; ++i) {
            int c = t + i * 256, row = c >> 3, kc = c & 7;
            rb[i] = *(const int4*)(W0 + (u64)row * 640 + k0 + kc * 8);
        }
        __syncthreads();   // prior iter's LDS reads done
#pragma unroll
        for (int i = 0; i < 2; ++i) {
            int c = t + i * 256, row = c >> 3, kc = c & 7;
            *(int4*)(&As[row][kc * 8]) = ra[i];
        }
#pragma unroll
        for (int i = 0; i < 8; ++i) {
            int c = t + i * 256, row = c >> 3, kc = c & 7;
            *(int4*)(&Bs[row][kc * 8]) = rb[i];
        }
        __syncthreads();
#pragma unroll
        for (int ks = 0; ks < 2; ++ks) {
            int kq = ks * 32 + (lane >> 4) * 8;
            s8v af = *(const s8v*)(&As[wid * 16 + (lane & 15)][kq]);
#pragma unroll
            for (int nt = 0; nt < 16; ++nt) {
                s8v bf = *(const s8v*)(&Bs[nt * 16 + (lane & 15)][kq]);
                acc[nt] = __builtin_amdgcn_mfma_f32_16x16x32_bf16(af, bf, acc[nt], 0, 0, 0);
            }
        }
    }
    // epilogue A: bias + BNx4(relu) chain + JK max -> zs (own wave band)
#pragma unroll
    for (int nt = 0; nt < 16; ++nt) {
        int col = nt * 16 + (lane & 15);
        float bv = b0v[col];
        float a_[4], c_[4];
#pragma unroll
        for (int i = 0; i < 4; ++i) {
            a_[i] = bn_a[i * 256 + col];
            c_[i] = bn_c[i * 256 + col];
        }
        int rb_ = wid * 16 + (lane >> 4) * 4;
#pragma unroll
        for (int r = 0; r < 4; ++r) {
            float h = acc[nt][r] + bv, z = 0.0f;
#pragma unroll
            for (int i = 0; i < 4; ++i) {
                h = fmaxf(fmaf(a_[i], h, c_[i]), 0.0f);
                z = fmaxf(z, h);
            }
            zs[rb_ + r][col] = f2bf(z);
        }
    }
    __syncthreads();   // zs published; also fences last phase-A Bs reads

    // ---------------- phase B: z2 = relu(z @ W1^T + b1) (K=256) ----------
#pragma unroll
    for (int j = 0; j < 16; ++j) acc[j] = (f4v){0.f, 0.f, 0.f, 0.f};
    for (int k0 = 0; k0 < 256; k0 += 64) {
        int4 rb[8];
#pragma unroll
        for (int i = 0; i < 8; ++i) {
            int c = t + i * 256, row = c >> 3, kc = c & 7;
            rb[i] = *(const int4*)(W1 + (u64)row * 256 + k0 + kc * 8);
        }
        __syncthreads();
#pragma unroll
        for (int i = 0; i < 8; ++i) {
            int c = t + i * 256, row = c >> 3, kc = c & 7;
            *(int4*)(&Bs[row][kc * 8]) = rb[i];
        }
        __syncthreads();
#pragma unroll
        for (int ks = 0; ks < 2; ++ks) {
            int kqr = ks * 32 + (lane >> 4) * 8;        // tile-relative: Bs
            s8v af = *(const s8v*)(&zs[wid * 16 + (lane & 15)][k0 + kqr]);  // absolute: zs
#pragma unroll
            for (int nt = 0; nt < 16; ++nt) {
                s8v bf = *(const s8v*)(&Bs[nt * 16 + (lane & 15)][kqr]);
                acc[nt] = __builtin_amdgcn_mfma_f32_16x16x32_bf16(af, bf, acc[nt], 0, 0, 0);
            }
        }
    }
    // epilogue B: relu -> z2 back into zs (same wave band; in-wave RAW only)
#pragma unroll
    for (int nt = 0; nt < 16; ++nt) {
        int col = nt * 16 + (lane & 15);
        float bv = b1v[col];
        int rb_ = wid * 16 + (lane >> 4) * 4;
#pragma unroll
        for (int r = 0; r < 4; ++r)
            zs[rb_ + r][col] = f2bf(fmaxf(acc[nt][r] + bv, 0.0f));
    }
    __syncthreads();

    // ---------------- phase C: lin2 + log_softmax ------------------------
    {
        int row = t >> 2, sub = t & 3;
        float a10[10];
#pragma unroll
        for (int o = 0; o < 10; ++o) a10[o] = 0.0f;
        const u32* zrow = (const u32*)(&zs[row][0]);
        for (int kk = sub * 32; kk < sub * 32 + 32; ++kk) {
            u32 pz = zrow[kk];
            float z0 = bf2f((u16)(pz & 0xFFFFu));
            float z1 = bf2f((u16)(pz >> 16));
#pragma unroll
            for (int o = 0; o < 10; ++o) {
                a10[o] = fmaf(z0, w2s[o * 256 + kk * 2], a10[o]);
                a10[o] = fmaf(z1, w2s[o * 256 + kk * 2 + 1], a10[o]);
            }
        }
#pragma unroll
        for (int o = 0; o < 10; ++o) {
            a10[o] += __shfl_xor(a10[o], 1);
            a10[o] += __shfl_xor(a10[o], 2);
        }
        if (sub == 0) {
            float l[10], mx = -1e30f;
#pragma unroll
            for (int o = 0; o < 10; ++o) { l[o] = a10[o] + b2s[o]; mx = fmaxf(mx, l[o]); }
            float s = 0.0f;
#pragma unroll
            for (int o = 0; o < 10; ++o) s += expf(l[o] - mx);
            float ls = logf(s);
            float* orow = out + (u64)(r0 + row) * 10;
#pragma unroll
            for (int o = 0; o < 10; ++o) orow[o] = l[o] - mx - ls;
        }
    }
}

// ---------------------------------------------------------------------------
extern "C" void kernel_launch(void* const* d_in, const int* in_sizes, int n_in,
                              void* d_out, int out_size, void* d_ws, size_t ws_size,
                              hipStream_t stream) {
    const float* x    = (const float*)d_in[0];
    const float* L    = (const float*)d_in[1];
    const float* lmax = (const float*)d_in[2];
    const float* cl1W = (const float*)d_in[3];
    const float* cl1b = (const float*)d_in[4];
    const float* fc1W = (const float*)d_in[5];
    const float* fc1b = (const float*)d_in[6];
    const float* gam  = (const float*)d_in[7];
    const float* bet  = (const float*)d_in[8];
    const float* mea  = (const float*)d_in[9];
    const float* var  = (const float*)d_in[10];
    const float* l1W  = (const float*)d_in[11];
    const float* l1b  = (const float*)d_in[12];
    const float* l2W  = (const float*)d_in[13];
    const float* l2b  = (const float*)d_in[14];

    char* ws = (char*)d_ws;
    u32*   packed  = (u32*)(ws + 0);          // 128000 -> 131072
    int*   cnts    = (int*)(ws + 131072);     // 4096
    float* diagw   = (float*)(ws + 135168);   // 4096
    float* bn_a    = (float*)(ws + 139264);   // 4096
    float* bn_c    = (float*)(ws + 143360);   // 4096
    u16*   fc1w_b  = (u16*)(ws + 147456);     // 327680
    u16*   lin1w_b = (u16*)(ws + 475136);     // 131072
    u16*   pooled  = (u16*)(ws + 606208);     // 10485760
    float* outp    = (float*)d_out;

    k_prep<<<dim3(890), dim3(256), 0, stream>>>(L, lmax, packed, cnts, diagw,
                                                fc1W, l1W, gam, bet, mea, var,
                                                fc1w_b, lin1w_b, bn_a, bn_c);
    k_cheby<<<dim3(1024), dim3(1024), 0, stream>>>(x, (const int4*)packed, cnts, diagw,
                                                   cl1W, cl1b, pooled);
    k_tail<<<dim3(128), dim3(256), 0, stream>>>(pooled, fc1w_b, fc1b, bn_a, bn_c,
                                                lin1w_b, l1b, l2W, l2b, outp);
}

// Round 10
// 247.594 us; speedup vs baseline: 1.0355x; 1.0355x over previous
//
#include <hip/hip_runtime.h>

typedef unsigned int u32;
typedef unsigned short u16;
typedef unsigned long long u64;

typedef __attribute__((ext_vector_type(8))) short s8v;   // 8 bf16 (4 VGPRs)
typedef __attribute__((ext_vector_type(4))) float f4v;   // 4 fp32 acc

#define B_SZ   8192
#define V_SZ   1000
#define KCH    5
#define MAXDEG 32

__device__ __forceinline__ u16 f2bf(float f) {
    u32 u = __float_as_uint(f);
    u32 r = (u + 0x7FFFu + ((u >> 16) & 1u)) >> 16;   // RNE
    return (u16)r;
}
__device__ __forceinline__ float bf2f(u16 h) { return __uint_as_float(((u32)h) << 16); }

// ---------------------------------------------------------------------------
// K0: fused prep = {sparse build of Lr} U {weight bf16 conversion + BN fold}.
// blocks 0..249: build (wave-per-row scan of dense L), blocks 250..889: conv.
// SPLIT sparse layout (r9): wts[q4*V+v][4] fp32 weights, colsu[q4*V+v][4] u16
// cols -> zero per-entry weight decode in k_cheby, full-precision weights.
// Tails zero-padded (col 0, weight 0): safe broadcast gathers in k_cheby.
// ---------------------------------------------------------------------------
__global__ __launch_bounds__(256) void k_prep(const float* __restrict__ L,
                                              const float* __restrict__ lmax,
                                              float* __restrict__ wts,
                                              u16* __restrict__ colsu,
                                              int* __restrict__ cnts,
                                              float* __restrict__ diagw,
                                              const float* __restrict__ fc1W,
                                              const float* __restrict__ lin1W,
                                              const float* __restrict__ gam,
                                              const float* __restrict__ bet,
                                              const float* __restrict__ mea,
                                              const float* __restrict__ var,
                                              u16* __restrict__ fc1w_b,
                                              u16* __restrict__ lin1w_b,
                                              float* __restrict__ bn_a,
                                              float* __restrict__ bn_c) {
    if (blockIdx.x < 250) {
        int wid  = threadIdx.x >> 6;
        int lane = threadIdx.x & 63;
        int row  = blockIdx.x * 4 + wid;
        if (row >= V_SZ) return;
        float s = 2.0f / lmax[0];
        const float* Lrow = L + (u64)row * V_SZ;
        int cnt = 0;
        for (int c0 = 0; c0 < V_SZ; c0 += 64) {
            int c = c0 + lane;
            float val = 0.0f;
            if (c < V_SZ && c != row) val = Lrow[c];
            bool nz = (val != 0.0f);
            u64 m = __ballot(nz);
            int pos = cnt + __popcll(m & ((1ull << lane) - 1ull));
            if (nz && pos < MAXDEG) {
                int idx = ((pos >> 2) * V_SZ + row) * 4 + (pos & 3);
                wts[idx]   = val * s;
                colsu[idx] = (u16)c;
            }
            cnt += __popcll(m);
        }
        int cc = cnt < MAXDEG ? cnt : MAXDEG;
        for (int e = cc + lane; e < MAXDEG; e += 64) {
            int idx = ((e >> 2) * V_SZ + row) * 4 + (e & 3);
            wts[idx]   = 0.0f;
            colsu[idx] = 0;
        }
        if (lane == 0) {
            cnts[row]  = cc;
            diagw[row] = s * Lrow[row] - 1.0f;
        }
    } else {
        int t = (blockIdx.x - 250) * 256 + threadIdx.x;
        if (t < 256 * 640) {
            int r = t / 640, c = t - r * 640;
            fc1w_b[t] = (c < 625) ? f2bf(fc1W[r * 625 + c]) : (u16)0;
        }
        if (t < 256 * 256) lin1w_b[t] = f2bf(lin1W[t]);
        if (t < 4 * 256) {
            float a = gam[t] * rsqrtf(var[t] + 1e-5f);
            bn_a[t] = a;
            bn_c[t] = bet[t] - mea[t] * a;
        }
    }
}

// ---------------------------------------------------------------------------
// K1: fused Chebyshev recursion + cl1 + ReLU + maxpool8 -> bf16.
// 512 thr, 2 rows/thread, 4 cols/block (r5 proven shape). r9 changes:
// - split wts/colsu loads: no weight decode, 1 bfe-class op per col
// - uniform branch-free loops to the WAVE max nq (6-shuffle reduce once);
//   tail quads gather buf[0] broadcast x 0-weight (exact, conflict-free)
// (512,4): 128-VGPR cap -- (512,8)'s 64-cap spilled 3.5 GB (round 3).
// ---------------------------------------------------------------------------
__global__ __launch_bounds__(512, 4) void k_cheby(const float* __restrict__ x,
                                                  const float4* __restrict__ wts4,
                                                  const uint2* __restrict__ cols2,
                                                  const int* __restrict__ cnts,
                                                  const float* __restrict__ diagw,
                                                  const float* __restrict__ cl1W,
                                                  const float* __restrict__ cl1b,
                                                  u16* __restrict__ pooled) {
    __shared__ float4 buf[2][V_SZ];   // [pingpong][v] = 4 batch cols, 32 KB
    __shared__ float cws[25];
    __shared__ float cbs[5];
    int t  = threadIdx.x;
    int b0 = blockIdx.x * 4;

    if (t < 25) cws[t] = cl1W[t];
    if (t < 5)  cbs[t] = cl1b[t];

    const int  v1   = t + 512;
    const bool val1 = (v1 < V_SZ);
    const int  v1c  = val1 ? v1 : (V_SZ - 1);   // clamped for structure loads

    float d0 = diagw[t];
    float d1 = val1 ? diagw[v1] : 0.0f;

    // wave-max loop bounds (uniform, branch-free inner loops)
    int m0 = (cnts[t] + 3) >> 2;
    int m1 = val1 ? ((cnts[v1] + 3) >> 2) : 0;
#pragma unroll
    for (int off = 1; off < 64; off <<= 1) {
        m0 = max(m0, __shfl_xor(m0, off));
        m1 = max(m1, __shfl_xor(m1, off));
    }

    // stage-0 staging: buf[0][v] = x[b0..b0+3][v]; own values kept in regs
    float4 pm1_0, pm2_0, pm1_1, pm2_1;
    {
        float4 a;
        a.x = x[(u64)(b0 + 0) * V_SZ + t];
        a.y = x[(u64)(b0 + 1) * V_SZ + t];
        a.z = x[(u64)(b0 + 2) * V_SZ + t];
        a.w = x[(u64)(b0 + 3) * V_SZ + t];
        buf[0][t] = a;
        pm1_0 = a; pm2_0 = a;
        float4 b = make_float4(0.f, 0.f, 0.f, 0.f);
        if (val1) {
            b.x = x[(u64)(b0 + 0) * V_SZ + v1];
            b.y = x[(u64)(b0 + 1) * V_SZ + v1];
            b.z = x[(u64)(b0 + 2) * V_SZ + v1];
            b.w = x[(u64)(b0 + 3) * V_SZ + v1];
            buf[0][v1] = b;
        }
        pm1_1 = b; pm2_1 = b;
    }
    __syncthreads();

    // feat init with k=0 term
    float4 feat0[5], feat1[5];
#pragma unroll
    for (int f = 0; f < 5; ++f) {
        float w = cws[f * 5];
        feat0[f] = make_float4(w * pm1_0.x, w * pm1_0.y, w * pm1_0.z, w * pm1_0.w);
        feat1[f] = make_float4(w * pm1_1.x, w * pm1_1.y, w * pm1_1.z, w * pm1_1.w);
    }

    // stages 1..4
#pragma unroll
    for (int k = 1; k < KCH; ++k) {
        const float4* prevb = buf[(k - 1) & 1];
        float4*       curb  = buf[k & 1];

        // ---- row 0 (v = t): uniform loop to wave max m0 ----
        {
            float4 a = make_float4(d0 * pm1_0.x, d0 * pm1_0.y,
                                   d0 * pm1_0.z, d0 * pm1_0.w);
            float4 wq = wts4[t];
            uint2  cq = cols2[t];
            for (int q = 0; q < m0; ++q) {
                float4 wqn = wts4[(q + 1) * V_SZ + t];    // coalesced; safe pad
                uint2  cqn = cols2[(q + 1) * V_SZ + t];
                float4 g0 = prevb[cq.x & 0xFFFFu];
                float4 g1 = prevb[cq.x >> 16];
                float4 g2 = prevb[cq.y & 0xFFFFu];
                float4 g3 = prevb[cq.y >> 16];
                a.x = fmaf(wq.x, g0.x, a.x); a.y = fmaf(wq.x, g0.y, a.y);
                a.z = fmaf(wq.x, g0.z, a.z); a.w = fmaf(wq.x, g0.w, a.w);
                a.x = fmaf(wq.y, g1.x, a.x); a.y = fmaf(wq.y, g1.y, a.y);
                a.z = fmaf(wq.y, g1.z, a.z); a.w = fmaf(wq.y, g1.w, a.w);
                a.x = fmaf(wq.z, g2.x, a.x); a.y = fmaf(wq.z, g2.y, a.y);
                a.z = fmaf(wq.z, g2.z, a.z); a.w = fmaf(wq.z, g2.w, a.w);
                a.x = fmaf(wq.w, g3.x, a.x); a.y = fmaf(wq.w, g3.y, a.y);
                a.z = fmaf(wq.w, g3.z, a.z); a.w = fmaf(wq.w, g3.w, a.w);
                wq = wqn; cq = cqn;
            }
            if (k >= 2) {
                a.x = fmaf(2.0f, a.x, -pm2_0.x);
                a.y = fmaf(2.0f, a.y, -pm2_0.y);
                a.z = fmaf(2.0f, a.z, -pm2_0.z);
                a.w = fmaf(2.0f, a.w, -pm2_0.w);
            }
            curb[t] = a;
            pm2_0 = pm1_0; pm1_0 = a;
#pragma unroll
            for (int f = 0; f < 5; ++f) {
                float w = cws[f * 5 + k];
                feat0[f].x = fmaf(w, a.x, feat0[f].x);
                feat0[f].y = fmaf(w, a.y, feat0[f].y);
                feat0[f].z = fmaf(w, a.z, feat0[f].z);
                feat0[f].w = fmaf(w, a.w, feat0[f].w);
            }
        }
        // ---- row 1 (v = t+512): uniform loop to wave max m1 ----
        {
            float4 a = make_float4(d1 * pm1_1.x, d1 * pm1_1.y,
                                   d1 * pm1_1.z, d1 * pm1_1.w);
            float4 wq = wts4[v1c];
            uint2  cq = cols2[v1c];
            for (int q = 0; q < m1; ++q) {
                float4 wqn = wts4[(q + 1) * V_SZ + v1c];
                uint2  cqn = cols2[(q + 1) * V_SZ + v1c];
                float4 g0 = prevb[cq.x & 0xFFFFu];
                float4 g1 = prevb[cq.x >> 16];
                float4 g2 = prevb[cq.y & 0xFFFFu];
                float4 g3 = prevb[cq.y >> 16];
                a.x = fmaf(wq.x, g0.x, a.x); a.y = fmaf(wq.x, g0.y, a.y);
                a.z = fmaf(wq.x, g0.z, a.z); a.w = fmaf(wq.x, g0.w, a.w);
                a.x = fmaf(wq.y, g1.x, a.x); a.y = fmaf(wq.y, g1.y, a.y);
                a.z = fmaf(wq.y, g1.z, a.z); a.w = fmaf(wq.y, g1.w, a.w);
                a.x = fmaf(wq.z, g2.x, a.x); a.y = fmaf(wq.z, g2.y, a.y);
                a.z = fmaf(wq.z, g2.z, a.z); a.w = fmaf(wq.z, g2.w, a.w);
                a.x = fmaf(wq.w, g3.x, a.x); a.y = fmaf(wq.w, g3.y, a.y);
                a.z = fmaf(wq.w, g3.z, a.z); a.w = fmaf(wq.w, g3.w, a.w);
                wq = wqn; cq = cqn;
            }
            if (k >= 2) {
                a.x = fmaf(2.0f, a.x, -pm2_1.x);
                a.y = fmaf(2.0f, a.y, -pm2_1.y);
                a.z = fmaf(2.0f, a.z, -pm2_1.z);
                a.w = fmaf(2.0f, a.w, -pm2_1.w);
            }
            if (val1) curb[v1] = a;
            pm2_1 = pm1_1; pm1_1 = a;
#pragma unroll
            for (int f = 0; f < 5; ++f) {
                float w = cws[f * 5 + k];
                feat1[f].x = fmaf(w, a.x, feat1[f].x);
                feat1[f].y = fmaf(w, a.y, feat1[f].y);
                feat1[f].z = fmaf(w, a.z, feat1[f].z);
                feat1[f].w = fmaf(w, a.w, feat1[f].w);
            }
        }
        __syncthreads();
    }

    // bias + ReLU + maxpool8 via 8-lane shuffle (8 consecutive t = 8 consecutive v)
#pragma unroll
    for (int f = 0; f < 5; ++f) {
#pragma unroll
        for (int b = 0; b < 4; ++b) {
            float c0 = (b == 0) ? feat0[f].x : (b == 1) ? feat0[f].y
                     : (b == 2) ? feat0[f].z : feat0[f].w;
            float s0 = fmaxf(c0 + cbs[f], 0.0f);
            s0 = fmaxf(s0, __shfl_xor(s0, 1));
            s0 = fmaxf(s0, __shfl_xor(s0, 2));
            s0 = fmaxf(s0, __shfl_xor(s0, 4));
            if ((t & 7) == 0)
                pooled[(u64)(b0 + b) * 640 + (t >> 3) * 5 + f] = f2bf(s0);

            float c1 = (b == 0) ? feat1[f].x : (b == 1) ? feat1[f].y
                     : (b == 2) ? feat1[f].z : feat1[f].w;
            float s1 = val1 ? fmaxf(c1 + cbs[f], 0.0f) : 0.0f;
            s1 = fmaxf(s1, __shfl_xor(s1, 1));
            s1 = fmaxf(s1, __shfl_xor(s1, 2));
            s1 = fmaxf(s1, __shfl_xor(s1, 4));
            if ((t & 7) == 0 && val1)
                pooled[(u64)(b0 + b) * 640 + (v1 >> 3) * 5 + f] = f2bf(s1);
        }
    }
    // zero the K-padding columns 625..639 for the 4 batch rows
    if (t < 60) {
        int b = t / 15, c = 625 + (t % 15);
        pooled[(u64)(b0 + b) * 640 + c] = 0;
    }
}

// ---------------------------------------------------------------------------
// K2: fused tail (round-7 proven). One block = 64 batch rows end-to-end:
//   z  = JKmax(BNx4(relu-chain)) of (pooled[64,640] @ fc1W^T + b)   -> LDS
//   z2 = relu(z @ lin1W^T + b1)                                    -> LDS
//   out= log_softmax(z2 @ l2W^T + b2)                              -> global
// Bs indices TILE-RELATIVE, zs ABSOLUTE (round-6 NaN bug).
// ---------------------------------------------------------------------------
__global__ __launch_bounds__(256) void k_tail(const u16* __restrict__ A,      // pooled [B,640]
                                              const u16* __restrict__ W0,     // fc1w_b [256,640]
                                              const float* __restrict__ b0v,  // fc1b
                                              const float* __restrict__ bn_a,
                                              const float* __restrict__ bn_c,
                                              const u16* __restrict__ W1,     // lin1w_b [256,256]
                                              const float* __restrict__ b1v,  // lin1b
                                              const float* __restrict__ W2,   // l2W [10,256] f32
                                              const float* __restrict__ b2v,  // l2b
                                              float* __restrict__ out) {
    __shared__ u16   As[64][72];
    __shared__ u16   Bs[256][72];
    __shared__ u16   zs[64][264];
    __shared__ float w2s[2560];
    __shared__ float b2s[10];
    int t    = threadIdx.x;
    int lane = t & 63;
    int wid  = t >> 6;
    int r0   = blockIdx.x * 64;

    for (int c = t; c < 2560; c += 256) w2s[c] = W2[c];
    if (t < 10) b2s[t] = b2v[t];

    f4v acc[16];
#pragma unroll
    for (int j = 0; j < 16; ++j) acc[j] = (f4v){0.f, 0.f, 0.f, 0.f};

    // ---------------- phase A: z = pooled @ W0^T (K=640) ----------------
    for (int k0 = 0; k0 < 640; k0 += 64) {
        int4 ra[2], rb[8];
#pragma unroll
        for (int i = 0; i < 2; ++i) {
            int c = t + i * 256, row = c >> 3, kc = c & 7;
            ra[i] = *(const int4*)(A + (u64)(r0 + row) * 640 + k0 + kc * 8);
        }
#pragma unroll
        for (int i = 0; i < 8; ++i) {
            int c = t + i * 256, row = c >> 3, kc = c & 7;
            rb[i] = *(const int4*)(W0 + (u64)row * 640 + k0 + kc * 8);
        }
        __syncthreads();
#pragma unroll
        for (int i = 0; i < 2; ++i) {
            int c = t + i * 256, row = c >> 3, kc = c & 7;
            *(int4*)(&As[row][kc * 8]) = ra[i];
        }
#pragma unroll
        for (int i = 0; i < 8; ++i) {
            int c = t + i * 256, row = c >> 3, kc = c & 7;
            *(int4*)(&Bs[row][kc * 8]) = rb[i];
        }
        __syncthreads();
#pragma unroll
        for (int ks = 0; ks < 2; ++ks) {
            int kq = ks * 32 + (lane >> 4) * 8;
            s8v af = *(const s8v*)(&As[wid * 16 + (lane & 15)][kq]);
#pragma unroll
            for (int nt = 0; nt < 16; ++nt) {
                s8v bf = *(const s8v*)(&Bs[nt * 16 + (lane & 15)][kq]);
                acc[nt] = __builtin_amdgcn_mfma_f32_16x16x32_bf16(af, bf, acc[nt], 0, 0, 0);
            }
        }
    }
#pragma unroll
    for (int nt = 0; nt < 16; ++nt) {
        int col = nt * 16 + (lane & 15);
        float bv = b0v[col];
        float a_[4], c_[4];
#pragma unroll
        for (int i = 0; i < 4; ++i) {
            a_[i] = bn_a[i * 256 + col];
            c_[i] = bn_c[i * 256 + col];
        }
        int rb_ = wid * 16 + (lane >> 4) * 4;
#pragma unroll
        for (int r = 0; r < 4; ++r) {
            float h = acc[nt][r] + bv, z = 0.0f;
#pragma unroll
            for (int i = 0; i < 4; ++i) {
                h = fmaxf(fmaf(a_[i], h, c_[i]), 0.0f);
                z = fmaxf(z, h);
            }
            zs[rb_ + r][col] = f2bf(z);
        }
    }
    __syncthreads();

    // ---------------- phase B: z2 = relu(z @ W1^T + b1) (K=256) ----------
#pragma unroll
    for (int j = 0; j < 16; ++j) acc[j] = (f4v){0.f, 0.f, 0.f, 0.f};
    for (int k0 = 0; k0 < 256; k0 += 64) {
        int4 rb[8];
#pragma unroll
        for (int i = 0; i < 8; ++i) {
            int c = t + i * 256, row = c >> 3, kc = c & 7;
            rb[i] = *(const int4*)(W1 + (u64)row * 256 + k0 + kc * 8);
        }
        __syncthreads();
#pragma unroll
        for (int i = 0; i < 8; ++i) {
            int c = t + i * 256, row = c >> 3, kc = c & 7;
            *(int4*)(&Bs[row][kc * 8]) = rb[i];
        }
        __syncthreads();
#pragma unroll
        for (int ks = 0; ks < 2; ++ks) {
            int kqr = ks * 32 + (lane >> 4) * 8;        // tile-relative: Bs
            s8v af = *(const s8v*)(&zs[wid * 16 + (lane & 15)][k0 + kqr]);  // absolute: zs
#pragma unroll
            for (int nt = 0; nt < 16; ++nt) {
                s8v bf = *(const s8v*)(&Bs[nt * 16 + (lane & 15)][kqr]);
                acc[nt] = __builtin_amdgcn_mfma_f32_16x16x32_bf16(af, bf, acc[nt], 0, 0, 0);
            }
        }
    }
#pragma unroll
    for (int nt = 0; nt < 16; ++nt) {
        int col = nt * 16 + (lane & 15);
        float bv = b1v[col];
        int rb_ = wid * 16 + (lane >> 4) * 4;
#pragma unroll
        for (int r = 0; r < 4; ++r)
            zs[rb_ + r][col] = f2bf(fmaxf(acc[nt][r] + bv, 0.0f));
    }
    __syncthreads();

    // ---------------- phase C: lin2 + log_softmax ------------------------
    {
        int row = t >> 2, sub = t & 3;
        float a10[10];
#pragma unroll
        for (int o = 0; o < 10; ++o) a10[o] = 0.0f;
        const u32* zrow = (const u32*)(&zs[row][0]);
        for (int kk = sub * 32; kk < sub * 32 + 32; ++kk) {
            u32 pz = zrow[kk];
            float z0 = bf2f((u16)(pz & 0xFFFFu));
            float z1 = bf2f((u16)(pz >> 16));
#pragma unroll
            for (int o = 0; o < 10; ++o) {
                a10[o] = fmaf(z0, w2s[o * 256 + kk * 2], a10[o]);
                a10[o] = fmaf(z1, w2s[o * 256 + kk * 2 + 1], a10[o]);
            }
        }
#pragma unroll
        for (int o = 0; o < 10; ++o) {
            a10[o] += __shfl_xor(a10[o], 1);
            a10[o] += __shfl_xor(a10[o], 2);
        }
        if (sub == 0) {
            float l[10], mx = -1e30f;
#pragma unroll
            for (int o = 0; o < 10; ++o) { l[o] = a10[o] + b2s[o]; mx = fmaxf(mx, l[o]); }
            float s = 0.0f;
#pragma unroll
            for (int o = 0; o < 10; ++o) s += expf(l[o] - mx);
            float ls = logf(s);
            float* orow = out + (u64)(r0 + row) * 10;
#pragma unroll
            for (int o = 0; o < 10; ++o) orow[o] = l[o] - mx - ls;
        }
    }
}

// ---------------------------------------------------------------------------
extern "C" void kernel_launch(void* const* d_in, const int* in_sizes, int n_in,
                              void* d_out, int out_size, void* d_ws, size_t ws_size,
                              hipStream_t stream) {
    const float* x    = (const float*)d_in[0];
    const float* L    = (const float*)d_in[1];
    const float* lmax = (const float*)d_in[2];
    const float* cl1W = (const float*)d_in[3];
    const float* cl1b = (const float*)d_in[4];
    const float* fc1W = (const float*)d_in[5];
    const float* fc1b = (const float*)d_in[6];
    const float* gam  = (const float*)d_in[7];
    const float* bet  = (const float*)d_in[8];
    const float* mea  = (const float*)d_in[9];
    const float* var  = (const float*)d_in[10];
    const float* l1W  = (const float*)d_in[11];
    const float* l1b  = (const float*)d_in[12];
    const float* l2W  = (const float*)d_in[13];
    const float* l2b  = (const float*)d_in[14];

    char* ws = (char*)d_ws;
    float* wts     = (float*)(ws + 0);        // 131072 (8*1000*4 f32)
    u16*   colsu   = (u16*)(ws + 131072);     // 65536  (8*1000*4 u16)
    int*   cnts    = (int*)(ws + 196608);     // 4096
    float* diagw   = (float*)(ws + 200704);   // 4096
    float* bn_a    = (float*)(ws + 204800);   // 4096
    float* bn_c    = (float*)(ws + 208896);   // 4096
    u16*   fc1w_b  = (u16*)(ws + 212992);     // 327680
    u16*   lin1w_b = (u16*)(ws + 540672);     // 131072
    u16*   pooled  = (u16*)(ws + 671744);     // 10485760 (total ~11.2 MB)
    float* outp    = (float*)d_out;

    k_prep<<<dim3(890), dim3(256), 0, stream>>>(L, lmax, wts, colsu, cnts, diagw,
                                                fc1W, l1W, gam, bet, mea, var,
                                                fc1w_b, lin1w_b, bn_a, bn_c);
    k_cheby<<<dim3(2048), dim3(512), 0, stream>>>(x, (const float4*)wts,
                                                  (const uint2*)colsu, cnts, diagw,
                                                  cl1W, cl1b, pooled);
    k_tail<<<dim3(128), dim3(256), 0, stream>>>(pooled, fc1w_b, fc1b, bn_a, bn_c,
                                                lin1w_b, l1b, l2W, l2b, outp);
}

// Round 11
// 237.558 us; speedup vs baseline: 1.0792x; 1.0422x over previous
//
#include <hip/hip_runtime.h>

typedef unsigned int u32;
typedef unsigned short u16;
typedef unsigned long long u64;

typedef __attribute__((ext_vector_type(8))) short s8v;   // 8 bf16 (4 VGPRs)
typedef __attribute__((ext_vector_type(4))) float f4v;   // 4 fp32 acc

#define B_SZ   8192
#define V_SZ   1000
#define KCH    5
#define MAXDEG 32

__device__ __forceinline__ u16 f2bf(float f) {
    u32 u = __float_as_uint(f);
    u32 r = (u + 0x7FFFu + ((u >> 16) & 1u)) >> 16;   // RNE
    return (u16)r;
}
__device__ __forceinline__ float bf2f(u16 h) { return __uint_as_float(((u32)h) << 16); }

// ---------------------------------------------------------------------------
// K0: fused prep = {sparse build of Lr} U {weight bf16 conversion + BN fold}.
// blocks 0..249: build (wave-per-row scan of dense L), blocks 250..889: conv.
// Split sparse layout: wts[q4*V+v][4] fp32, colsu[q4*V+v][4] u16 (transposed,
// coalesced in k_cheby). Tails zero-padded (col 0, weight 0).
// ---------------------------------------------------------------------------
__global__ __launch_bounds__(256) void k_prep(const float* __restrict__ L,
                                              const float* __restrict__ lmax,
                                              float* __restrict__ wts,
                                              u16* __restrict__ colsu,
                                              int* __restrict__ cnts,
                                              float* __restrict__ diagw,
                                              const float* __restrict__ fc1W,
                                              const float* __restrict__ lin1W,
                                              const float* __restrict__ gam,
                                              const float* __restrict__ bet,
                                              const float* __restrict__ mea,
                                              const float* __restrict__ var,
                                              u16* __restrict__ fc1w_b,
                                              u16* __restrict__ lin1w_b,
                                              float* __restrict__ bn_a,
                                              float* __restrict__ bn_c) {
    if (blockIdx.x < 250) {
        int wid  = threadIdx.x >> 6;
        int lane = threadIdx.x & 63;
        int row  = blockIdx.x * 4 + wid;
        if (row >= V_SZ) return;
        float s = 2.0f / lmax[0];
        const float* Lrow = L + (u64)row * V_SZ;
        int cnt = 0;
        for (int c0 = 0; c0 < V_SZ; c0 += 64) {
            int c = c0 + lane;
            float val = 0.0f;
            if (c < V_SZ && c != row) val = Lrow[c];
            bool nz = (val != 0.0f);
            u64 m = __ballot(nz);
            int pos = cnt + __popcll(m & ((1ull << lane) - 1ull));
            if (nz && pos < MAXDEG) {
                int idx = ((pos >> 2) * V_SZ + row) * 4 + (pos & 3);
                wts[idx]   = val * s;
                colsu[idx] = (u16)c;
            }
            cnt += __popcll(m);
        }
        int cc = cnt < MAXDEG ? cnt : MAXDEG;
        for (int e = cc + lane; e < MAXDEG; e += 64) {
            int idx = ((e >> 2) * V_SZ + row) * 4 + (e & 3);
            wts[idx]   = 0.0f;
            colsu[idx] = 0;
        }
        if (lane == 0) {
            cnts[row]  = cc;
            diagw[row] = s * Lrow[row] - 1.0f;
        }
    } else {
        int t = (blockIdx.x - 250) * 256 + threadIdx.x;
        if (t < 256 * 640) {
            int r = t / 640, c = t - r * 640;
            fc1w_b[t] = (c < 625) ? f2bf(fc1W[r * 625 + c]) : (u16)0;
        }
        if (t < 256 * 256) lin1w_b[t] = f2bf(lin1W[t]);
        if (t < 4 * 256) {
            float a = gam[t] * rsqrtf(var[t] + 1e-5f);
            bn_a[t] = a;
            bn_c[t] = bet[t] - mea[t] * a;
        }
    }
}

// ---------------------------------------------------------------------------
// K1: fused Chebyshev recursion + cl1 + ReLU + maxpool8 -> bf16.
// 1024 thr, 1 row/thread, 8 batch cols/block via TWO float4 arrays:
// buf[0..1][v] = cols 0-3 pingpong, buf[2..3][v] = cols 4-7 pingpong.
// Each gather = 2x ds_read_b128 from SEPARATE arrays whose bases are
// =0 mod 32 banks apart -> both keep the v%8 bank spread (r8's fused float8
// had v%4 -> 1.76e7 conflicts). Decode/address amortized over 8 cols.
// Per-thread nq loop with prefetch (r5/r7 proven). 1024-thr => 128-VGPR cap.
// ---------------------------------------------------------------------------
__global__ __launch_bounds__(1024) void k_cheby(const float* __restrict__ x,
                                                const float4* __restrict__ wts4,
                                                const uint2* __restrict__ cols2,
                                                const int* __restrict__ cnts,
                                                const float* __restrict__ diagw,
                                                const float* __restrict__ cl1W,
                                                const float* __restrict__ cl1b,
                                                u16* __restrict__ pooled) {
    __shared__ float4 buf[4][V_SZ];   // [0..1]=cols0-3 pp, [2..3]=cols4-7 pp; 64KB
    __shared__ float cws[25];
    __shared__ float cbs[5];
    int t  = threadIdx.x;
    int b0 = blockIdx.x * 8;

    if (t < 25) cws[t] = cl1W[t];
    if (t < 5)  cbs[t] = cl1b[t];

    const bool own = (t < V_SZ);
    const int  tc  = own ? t : (V_SZ - 1);    // clamped for structure loads

    float d0 = own ? diagw[tc] : 0.0f;
    int   n0 = own ? ((cnts[tc] + 3) >> 2) : 0;

    // stage-0 staging; own values kept in registers
    float4 pm1l = make_float4(0.f, 0.f, 0.f, 0.f), pm1h = pm1l, pm2l, pm2h;
    if (own) {
        pm1l.x = x[(u64)(b0 + 0) * V_SZ + t];
        pm1l.y = x[(u64)(b0 + 1) * V_SZ + t];
        pm1l.z = x[(u64)(b0 + 2) * V_SZ + t];
        pm1l.w = x[(u64)(b0 + 3) * V_SZ + t];
        pm1h.x = x[(u64)(b0 + 4) * V_SZ + t];
        pm1h.y = x[(u64)(b0 + 5) * V_SZ + t];
        pm1h.z = x[(u64)(b0 + 6) * V_SZ + t];
        pm1h.w = x[(u64)(b0 + 7) * V_SZ + t];
        buf[0][t] = pm1l;
        buf[2][t] = pm1h;
    }
    pm2l = pm1l; pm2h = pm1h;
    __syncthreads();

    // feat init with k=0 term
    float4 fl[5], fh[5];
#pragma unroll
    for (int f = 0; f < 5; ++f) {
        float w = cws[f * 5];
        fl[f] = make_float4(w * pm1l.x, w * pm1l.y, w * pm1l.z, w * pm1l.w);
        fh[f] = make_float4(w * pm1h.x, w * pm1h.y, w * pm1h.z, w * pm1h.w);
    }

    // stages 1..4 (k unrolled -> buf indices are compile-time)
#pragma unroll
    for (int k = 1; k < KCH; ++k) {
        const float4* plo = buf[(k - 1) & 1];
        const float4* phi = buf[2 + ((k - 1) & 1)];
        float4*       clo = buf[k & 1];
        float4*       chi = buf[2 + (k & 1)];

        if (own) {
            float4 al = make_float4(d0 * pm1l.x, d0 * pm1l.y, d0 * pm1l.z, d0 * pm1l.w);
            float4 ah = make_float4(d0 * pm1h.x, d0 * pm1h.y, d0 * pm1h.z, d0 * pm1h.w);
            float4 wq = wts4[tc];
            uint2  cq = cols2[tc];
            for (int q = 0; q < n0; ++q) {
                float4 wqn = wq;
                uint2  cqn = cq;
                if (q + 1 < n0) {
                    wqn = wts4[(q + 1) * V_SZ + tc];      // coalesced
                    cqn = cols2[(q + 1) * V_SZ + tc];
                }
                u32 c0i = cq.x & 0xFFFFu, c1i = cq.x >> 16;
                u32 c2i = cq.y & 0xFFFFu, c3i = cq.y >> 16;
                float4 g0l = plo[c0i], g0h = phi[c0i];
                float4 g1l = plo[c1i], g1h = phi[c1i];
                float4 g2l = plo[c2i], g2h = phi[c2i];
                float4 g3l = plo[c3i], g3h = phi[c3i];
                al.x = fmaf(wq.x, g0l.x, al.x); al.y = fmaf(wq.x, g0l.y, al.y);
                al.z = fmaf(wq.x, g0l.z, al.z); al.w = fmaf(wq.x, g0l.w, al.w);
                ah.x = fmaf(wq.x, g0h.x, ah.x); ah.y = fmaf(wq.x, g0h.y, ah.y);
                ah.z = fmaf(wq.x, g0h.z, ah.z); ah.w = fmaf(wq.x, g0h.w, ah.w);
                al.x = fmaf(wq.y, g1l.x, al.x); al.y = fmaf(wq.y, g1l.y, al.y);
                al.z = fmaf(wq.y, g1l.z, al.z); al.w = fmaf(wq.y, g1l.w, al.w);
                ah.x = fmaf(wq.y, g1h.x, ah.x); ah.y = fmaf(wq.y, g1h.y, ah.y);
                ah.z = fmaf(wq.y, g1h.z, ah.z); ah.w = fmaf(wq.y, g1h.w, ah.w);
                al.x = fmaf(wq.z, g2l.x, al.x); al.y = fmaf(wq.z, g2l.y, al.y);
                al.z = fmaf(wq.z, g2l.z, al.z); al.w = fmaf(wq.z, g2l.w, al.w);
                ah.x = fmaf(wq.z, g2h.x, ah.x); ah.y = fmaf(wq.z, g2h.y, ah.y);
                ah.z = fmaf(wq.z, g2h.z, ah.z); ah.w = fmaf(wq.z, g2h.w, ah.w);
                al.x = fmaf(wq.w, g3l.x, al.x); al.y = fmaf(wq.w, g3l.y, al.y);
                al.z = fmaf(wq.w, g3l.z, al.z); al.w = fmaf(wq.w, g3l.w, al.w);
                ah.x = fmaf(wq.w, g3h.x, ah.x); ah.y = fmaf(wq.w, g3h.y, ah.y);
                ah.z = fmaf(wq.w, g3h.z, ah.z); ah.w = fmaf(wq.w, g3h.w, ah.w);
                wq = wqn; cq = cqn;
            }
            if (k >= 2) {
                al.x = fmaf(2.0f, al.x, -pm2l.x); al.y = fmaf(2.0f, al.y, -pm2l.y);
                al.z = fmaf(2.0f, al.z, -pm2l.z); al.w = fmaf(2.0f, al.w, -pm2l.w);
                ah.x = fmaf(2.0f, ah.x, -pm2h.x); ah.y = fmaf(2.0f, ah.y, -pm2h.y);
                ah.z = fmaf(2.0f, ah.z, -pm2h.z); ah.w = fmaf(2.0f, ah.w, -pm2h.w);
            }
            clo[t] = al;
            chi[t] = ah;
            pm2l = pm1l; pm2h = pm1h;
            pm1l = al;   pm1h = ah;
#pragma unroll
            for (int f = 0; f < 5; ++f) {
                float w = cws[f * 5 + k];
                fl[f].x = fmaf(w, al.x, fl[f].x); fl[f].y = fmaf(w, al.y, fl[f].y);
                fl[f].z = fmaf(w, al.z, fl[f].z); fl[f].w = fmaf(w, al.w, fl[f].w);
                fh[f].x = fmaf(w, ah.x, fh[f].x); fh[f].y = fmaf(w, ah.y, fh[f].y);
                fh[f].z = fmaf(w, ah.z, fh[f].z); fh[f].w = fmaf(w, ah.w, fh[f].w);
            }
        }
        __syncthreads();
    }

    // bias + ReLU + maxpool8 via 8-lane shuffle (8 consecutive t = 8 consecutive v)
#pragma unroll
    for (int f = 0; f < 5; ++f) {
#pragma unroll
        for (int b = 0; b < 8; ++b) {
            float c0 = (b == 0) ? fl[f].x : (b == 1) ? fl[f].y
                     : (b == 2) ? fl[f].z : (b == 3) ? fl[f].w
                     : (b == 4) ? fh[f].x : (b == 5) ? fh[f].y
                     : (b == 6) ? fh[f].z : fh[f].w;
            float s = own ? fmaxf(c0 + cbs[f], 0.0f) : 0.0f;
            s = fmaxf(s, __shfl_xor(s, 1));
            s = fmaxf(s, __shfl_xor(s, 2));
            s = fmaxf(s, __shfl_xor(s, 4));
            if ((t & 7) == 0 && own)
                pooled[(u64)(b0 + b) * 640 + (t >> 3) * 5 + f] = f2bf(s);
        }
    }
    // zero the K-padding columns 625..639 for the 8 batch rows
    if (t < 120) {
        int b = t / 15, c = 625 + (t % 15);
        pooled[(u64)(b0 + b) * 640 + c] = 0;
    }
}

// ---------------------------------------------------------------------------
// K2: fused tail (round-7 proven). One block = 64 batch rows end-to-end:
//   z  = JKmax(BNx4(relu-chain)) of (pooled[64,640] @ fc1W^T + b)   -> LDS
//   z2 = relu(z @ lin1W^T + b1)                                    -> LDS
//   out= log_softmax(z2 @ l2W^T + b2)                              -> global
// Bs indices TILE-RELATIVE, zs ABSOLUTE (round-6 NaN bug).
// ---------------------------------------------------------------------------
__global__ __launch_bounds__(256) void k_tail(const u16* __restrict__ A,      // pooled [B,640]
                                              const u16* __restrict__ W0,     // fc1w_b [256,640]
                                              const float* __restrict__ b0v,  // fc1b
                                              const float* __restrict__ bn_a,
                                              const float* __restrict__ bn_c,
                                              const u16* __restrict__ W1,     // lin1w_b [256,256]
                                              const float* __restrict__ b1v,  // lin1b
                                              const float* __restrict__ W2,   // l2W [10,256] f32
                                              const float* __restrict__ b2v,  // l2b
                                              float* __restrict__ out) {
    __shared__ u16   As[64][72];
    __shared__ u16   Bs[256][72];
    __shared__ u16   zs[64][264];
    __shared__ float w2s[2560];
    __shared__ float b2s[10];
    int t    = threadIdx.x;
    int lane = t & 63;
    int wid  = t >> 6;
    int r0   = blockIdx.x * 64;

    for (int c = t; c < 2560; c += 256) w2s[c] = W2[c];
    if (t < 10) b2s[t] = b2v[t];

    f4v acc[16];
#pragma unroll
    for (int j = 0; j < 16; ++j) acc[j] = (f4v){0.f, 0.f, 0.f, 0.f};

    // ---------------- phase A: z = pooled @ W0^T (K=640) ----------------
    for (int k0 = 0; k0 < 640; k0 += 64) {
        int4 ra[2], rb[8];
#pragma unroll
        for (int i = 0; i < 2; ++i) {
            int c = t + i * 256, row = c >> 3, kc = c & 7;
            ra[i] = *(const int4*)(A + (u64)(r0 + row) * 640 + k0 + kc * 8);
        }
#pragma unroll
        for (int i = 0; i < 8; ++i) {
            int c = t + i * 256, row = c >> 3, kc = c & 7;
            rb[i] = *(const int4*)(W0 + (u64)row * 640 + k0 + kc * 8);
        }
        __syncthreads();
#pragma unroll
        for (int i = 0; i < 2; ++i) {
            int c = t + i * 256, row = c >> 3, kc = c & 7;
            *(int4*)(&As[row][kc * 8]) = ra[i];
        }
#pragma unroll
        for (int i = 0; i < 8; ++i) {
            int c = t + i * 256, row = c >> 3, kc = c & 7;
            *(int4*)(&Bs[row][kc * 8]) = rb[i];
        }
        __syncthreads();
#pragma unroll
        for (int ks = 0; ks < 2; ++ks) {
            int kq = ks * 32 + (lane >> 4) * 8;
            s8v af = *(const s8v*)(&As[wid * 16 + (lane & 15)][kq]);
#pragma unroll
            for (int nt = 0; nt < 16; ++nt) {
                s8v bf = *(const s8v*)(&Bs[nt * 16 + (lane & 15)][kq]);
                acc[nt] = __builtin_amdgcn_mfma_f32_16x16x32_bf16(af, bf, acc[nt], 0, 0, 0);
            }
        }
    }
#pragma unroll
    for (int nt = 0; nt < 16; ++nt) {
        int col = nt * 16 + (lane & 15);
        float bv = b0v[col];
        float a_[4], c_[4];
#pragma unroll
        for (int i = 0; i < 4; ++i) {
            a_[i] = bn_a[i * 256 + col];
            c_[i] = bn_c[i * 256 + col];
        }
        int rb_ = wid * 16 + (lane >> 4) * 4;
#pragma unroll
        for (int r = 0; r < 4; ++r) {
            float h = acc[nt][r] + bv, z = 0.0f;
#pragma unroll
            for (int i = 0; i < 4; ++i) {
                h = fmaxf(fmaf(a_[i], h, c_[i]), 0.0f);
                z = fmaxf(z, h);
            }
            zs[rb_ + r][col] = f2bf(z);
        }
    }
    __syncthreads();

    // ---------------- phase B: z2 = relu(z @ W1^T + b1) (K=256) ----------
#pragma unroll
    for (int j = 0; j < 16; ++j) acc[j] = (f4v){0.f, 0.f, 0.f, 0.f};
    for (int k0 = 0; k0 < 256; k0 += 64) {
        int4 rb[8];
#pragma unroll
        for (int i = 0; i < 8; ++i) {
            int c = t + i * 256, row = c >> 3, kc = c & 7;
            rb[i] = *(const int4*)(W1 + (u64)row * 256 + k0 + kc * 8);
        }
        __syncthreads();
#pragma unroll
        for (int i = 0; i < 8; ++i) {
            int c = t + i * 256, row = c >> 3, kc = c & 7;
            *(int4*)(&Bs[row][kc * 8]) = rb[i];
        }
        __syncthreads();
#pragma unroll
        for (int ks = 0; ks < 2; ++ks) {
            int kqr = ks * 32 + (lane >> 4) * 8;        // tile-relative: Bs
            s8v af = *(const s8v*)(&zs[wid * 16 + (lane & 15)][k0 + kqr]);  // absolute: zs
#pragma unroll
            for (int nt = 0; nt < 16; ++nt) {
                s8v bf = *(const s8v*)(&Bs[nt * 16 + (lane & 15)][kqr]);
                acc[nt] = __builtin_amdgcn_mfma_f32_16x16x32_bf16(af, bf, acc[nt], 0, 0, 0);
            }
        }
    }
#pragma unroll
    for (int nt = 0; nt < 16; ++nt) {
        int col = nt * 16 + (lane & 15);
        float bv = b1v[col];
        int rb_ = wid * 16 + (lane >> 4) * 4;
#pragma unroll
        for (int r = 0; r < 4; ++r)
            zs[rb_ + r][col] = f2bf(fmaxf(acc[nt][r] + bv, 0.0f));
    }
    __syncthreads();

    // ---------------- phase C: lin2 + log_softmax ------------------------
    {
        int row = t >> 2, sub = t & 3;
        float a10[10];
#pragma unroll
        for (int o = 0; o < 10; ++o) a10[o] = 0.0f;
        const u32* zrow = (const u32*)(&zs[row][0]);
        for (int kk = sub * 32; kk < sub * 32 + 32; ++kk) {
            u32 pz = zrow[kk];
            float z0 = bf2f((u16)(pz & 0xFFFFu));
            float z1 = bf2f((u16)(pz >> 16));
#pragma unroll
            for (int o = 0; o < 10; ++o) {
                a10[o] = fmaf(z0, w2s[o * 256 + kk * 2], a10[o]);
                a10[o] = fmaf(z1, w2s[o * 256 + kk * 2 + 1], a10[o]);
            }
        }
#pragma unroll
        for (int o = 0; o < 10; ++o) {
            a10[o] += __shfl_xor(a10[o], 1);
            a10[o] += __shfl_xor(a10[o], 2);
        }
        if (sub == 0) {
            float l[10], mx = -1e30f;
#pragma unroll
            for (int o = 0; o < 10; ++o) { l[o] = a10[o] + b2s[o]; mx = fmaxf(mx, l[o]); }
            float s = 0.0f;
#pragma unroll
            for (int o = 0; o < 10; ++o) s += expf(l[o] - mx);
            float ls = logf(s);
            float* orow = out + (u64)(r0 + row) * 10;
#pragma unroll
            for (int o = 0; o < 10; ++o) orow[o] = l[o] - mx - ls;
        }
    }
}

// ---------------------------------------------------------------------------
extern "C" void kernel_launch(void* const* d_in, const int* in_sizes, int n_in,
                              void* d_out, int out_size, void* d_ws, size_t ws_size,
                              hipStream_t stream) {
    const float* x    = (const float*)d_in[0];
    const float* L    = (const float*)d_in[1];
    const float* lmax = (const float*)d_in[2];
    const float* cl1W = (const float*)d_in[3];
    const float* cl1b = (const float*)d_in[4];
    const float* fc1W = (const float*)d_in[5];
    const float* fc1b = (const float*)d_in[6];
    const float* gam  = (const float*)d_in[7];
    const float* bet  = (const float*)d_in[8];
    const float* mea  = (const float*)d_in[9];
    const float* var  = (const float*)d_in[10];
    const float* l1W  = (const float*)d_in[11];
    const float* l1b  = (const float*)d_in[12];
    const float* l2W  = (const float*)d_in[13];
    const float* l2b  = (const float*)d_in[14];

    char* ws = (char*)d_ws;
    float* wts     = (float*)(ws + 0);        // 131072 (8*1000*4 f32)
    u16*   colsu   = (u16*)(ws + 131072);     // 65536  (8*1000*4 u16)
    int*   cnts    = (int*)(ws + 196608);     // 4096
    float* diagw   = (float*)(ws + 200704);   // 4096
    float* bn_a    = (float*)(ws + 204800);   // 4096
    float* bn_c    = (float*)(ws + 208896);   // 4096
    u16*   fc1w_b  = (u16*)(ws + 212992);     // 327680
    u16*   lin1w_b = (u16*)(ws + 540672);     // 131072
    u16*   pooled  = (u16*)(ws + 671744);     // 10485760 (total ~11.2 MB)
    float* outp    = (float*)d_out;

    k_prep<<<dim3(890), dim3(256), 0, stream>>>(L, lmax, wts, colsu, cnts, diagw,
                                                fc1W, l1W, gam, bet, mea, var,
                                                fc1w_b, lin1w_b, bn_a, bn_c);
    k_cheby<<<dim3(1024), dim3(1024), 0, stream>>>(x, (const float4*)wts,
                                                   (const uint2*)colsu, cnts, diagw,
                                                   cl1W, cl1b, pooled);
    k_tail<<<dim3(128), dim3(256), 0, stream>>>(pooled, fc1w_b, fc1b, bn_a, bn_c,
                                                lin1w_b, l1b, l2W, l2b, outp);
}